// Round 6
// baseline (354.221 us; speedup 1.0000x reference)
//
#include <hip/hip_runtime.h>

#define D 128
#define NC 40

typedef __attribute__((ext_vector_type(8))) short short8v;
typedef __attribute__((ext_vector_type(4))) float f32x4;

__device__ __forceinline__ unsigned short f2bf(float f) {
    unsigned u = __float_as_uint(f);
    u += 0x7fff + ((u >> 16) & 1);          // RNE
    return (unsigned short)(u >> 16);
}
__device__ __forceinline__ float bf2f(unsigned short h) {
    return __uint_as_float(((unsigned)h) << 16);
}

// ---------------- graph build ----------------

__global__ void detect_kernel(const int* __restrict__ ei, int* __restrict__ flag) {
    __shared__ int any;
    if (threadIdx.x == 0) any = 0;
    __syncthreads();
    if (ei[threadIdx.x * 2 + 1] != 0) any = 1;   // benign race
    __syncthreads();
    if (threadIdx.x == 0) *flag = (any == 0) ? 1 : 0;  // 1 == int64
}

__device__ __forceinline__ int load_idx(const int* ei, long long pos, int is64) {
    return is64 ? ei[pos * 2] : ei[pos];
}

__global__ void count_deg_kernel(const int* __restrict__ ei, const int* __restrict__ flag,
                                 int* __restrict__ deg, int E) {
    int e = blockIdx.x * blockDim.x + threadIdx.x;
    if (e >= E) return;
    int is64 = *flag;
    int d = load_idx(ei, (long long)E + e, is64);   // dst row
    atomicAdd(&deg[d], 1);
}

// 3-phase parallel exclusive scan over n entries (512-thread blocks)
__global__ void scan1_kernel(const int* __restrict__ deg, int* __restrict__ bsum, int m) {
    int i = blockIdx.x * 512 + threadIdx.x;
    int v = (i < m) ? deg[i] : 0;
    #pragma unroll
    for (int off = 32; off; off >>= 1) v += __shfl_down(v, off, 64);
    __shared__ int ws[8];
    if ((threadIdx.x & 63) == 0) ws[threadIdx.x >> 6] = v;
    __syncthreads();
    if (threadIdx.x == 0) {
        int s = 0;
        #pragma unroll
        for (int j = 0; j < 8; ++j) s += ws[j];
        bsum[blockIdx.x] = s;
    }
}

__global__ void scan2_kernel(int* __restrict__ bsum, int* __restrict__ total, int nb) {
    int t = threadIdx.x;                 // 1024 threads, nb <= 1024
    int lane = t & 63, w = t >> 6;
    int v = (t < nb) ? bsum[t] : 0;
    int s = v;
    #pragma unroll
    for (int off = 1; off < 64; off <<= 1) {
        int x = __shfl_up(s, off, 64);
        if (lane >= off) s += x;
    }
    __shared__ int wsum[16];
    if (lane == 63) wsum[w] = s;
    __syncthreads();
    int wbase = 0;
    #pragma unroll
    for (int j = 0; j < 16; ++j) if (j < w) wbase += wsum[j];
    int excl = wbase + s - v;
    if (t < nb) bsum[t] = excl;
    if (t == nb - 1) *total = excl + v;
}

// local scan + emit rowptr/fill + dinv (folded)
__global__ void scan3_kernel(const int* __restrict__ deg, const int* __restrict__ bsum,
                             const int* __restrict__ total, int* __restrict__ rowptr,
                             int* __restrict__ fill, float* __restrict__ dinv, int m) {
    int i = blockIdx.x * 512 + threadIdx.x;
    int v = (i < m) ? deg[i] : 0;
    int lane = threadIdx.x & 63, w = threadIdx.x >> 6;
    int s = v;
    #pragma unroll
    for (int off = 1; off < 64; off <<= 1) {
        int x = __shfl_up(s, off, 64);
        if (lane >= off) s += x;
    }
    __shared__ int wsum[8];
    if (lane == 63) wsum[w] = s;
    __syncthreads();
    int wbase = 0;
    #pragma unroll
    for (int j = 0; j < 8; ++j) if (j < w) wbase += wsum[j];
    int excl = bsum[blockIdx.x] + wbase + s - v;
    if (i < m) {
        rowptr[i] = excl;
        fill[i]   = excl;
        dinv[i]   = rsqrtf((float)(v + 1));   // +1 self loop
    }
    if (i == 0) rowptr[m] = *total;
}

// scatter edge -> CSR, packing {src, dinv[src]}
__global__ void scatter_kernel(const int* __restrict__ ei, const int* __restrict__ flag,
                               int* __restrict__ fill, const float* __restrict__ dinv,
                               int2* __restrict__ col2, int E) {
    int e = blockIdx.x * blockDim.x + threadIdx.x;
    if (e >= E) return;
    int is64 = *flag;
    int s = load_idx(ei, (long long)e, is64);
    int d = load_idx(ei, (long long)E + e, is64);
    int pos = atomicAdd(&fill[d], 1);
    col2[pos] = make_int2(s, __float_as_int(dinv[s]));
}

// ---------------- all-weights pre-conversion (one launch) ----------------
// f32 [k][N] -> hi plane + lo plane, [n][k] layout. W1,Wh0,Wh1: 128x128; Wf: 40->48 pad.
__global__ void convertW_all_kernel(const float* __restrict__ W1, const float* __restrict__ Wh,
                                    const float* __restrict__ Wf,
                                    unsigned short* __restrict__ Wc1, unsigned short* __restrict__ Wch0,
                                    unsigned short* __restrict__ Wch1, unsigned short* __restrict__ Wcf) {
    int idx = blockIdx.x * 256 + threadIdx.x;    // 0 .. 55295
    if (idx < 49152) {
        int which = idx >> 14;                   // 0,1,2
        int j = idx & 16383;
        int nn = j >> 7, k = j & 127;
        const float* W = (which == 0) ? W1 : (which == 1) ? Wh : Wh + 16384;
        unsigned short* o = (which == 0) ? Wc1 : (which == 1) ? Wch0 : Wch1;
        float v = W[k * 128 + nn];
        unsigned short h = f2bf(v);
        o[j] = h;
        o[16384 + j] = f2bf(v - bf2f(h));
    } else if (idx < 49152 + 6144) {
        int j = idx - 49152;
        int nn = j >> 7, k = j & 127;
        float v = (nn < NC) ? Wf[k * NC + nn] : 0.f;
        unsigned short h = f2bf(v);
        Wcf[j] = h;
        Wcf[6144 + j] = f2bf(v - bf2f(h));
    }
}

// ---------------- MFMA core shared pieces (macros to keep variants in sync) ----
// frag read offsets use XOR swizzle: off = row*256 + (col16*16 ^ ((row&7)<<4))

// ---- GEMM layer 1: f32 input (x), planes output ----
__launch_bounds__(256)
__global__ void gemm128_f32in_kernel(const float* __restrict__ A, const unsigned short* __restrict__ Wcvt,
                                     unsigned short* __restrict__ Chi, unsigned short* __restrict__ Clo, int M) {
    __shared__ unsigned short Ah[64 * 128];
    __shared__ unsigned short Al[64 * 128];
    int t = threadIdx.x;
    int l = t & 63, w = t >> 6;
    int lr = l & 15, lh = l >> 4;

    const unsigned short* Whi = Wcvt;               // [128n][128k]
    const unsigned short* Wlo = Wcvt + 128 * 128;
    short8v bhi[2][4], blo[2][4];
    int n0 = w * 32;
    #pragma unroll
    for (int ni = 0; ni < 2; ++ni) {
        int n = n0 + ni * 16 + lr;
        #pragma unroll
        for (int ks = 0; ks < 4; ++ks) {
            bhi[ni][ks] = *(const short8v*)&Whi[n * 128 + ks * 32 + lh * 8];
            blo[ni][ks] = *(const short8v*)&Wlo[n * 128 + ks * 32 + lh * 8];
        }
    }

    int row0 = blockIdx.x * 64;
    #pragma unroll
    for (int c = 0; c < 4; ++c) {
        int chunk = c * 256 + t;
        int r  = chunk >> 4;
        int kc = chunk & 15;
        int gr = row0 + r; if (gr >= M) gr = M - 1;
        float4 a0 = *(const float4*)&A[(size_t)gr * 128 + kc * 8];
        float4 a1 = *(const float4*)&A[(size_t)gr * 128 + kc * 8 + 4];
        float av[8] = {a0.x, a0.y, a0.z, a0.w, a1.x, a1.y, a1.z, a1.w};
        short8v hv, lv;
        #pragma unroll
        for (int j = 0; j < 8; ++j) {
            unsigned short hi = f2bf(av[j]);
            hv[j] = (short)hi;
            lv[j] = (short)f2bf(av[j] - bf2f(hi));
        }
        int off = (r << 8) + ((kc << 4) ^ ((r & 7) << 4));
        *(short8v*)((char*)Ah + off) = hv;
        *(short8v*)((char*)Al + off) = lv;
    }
    __syncthreads();

    f32x4 acc[4][2];
    #pragma unroll
    for (int mi = 0; mi < 4; ++mi)
        #pragma unroll
        for (int ni = 0; ni < 2; ++ni)
            acc[mi][ni] = (f32x4){0.f, 0.f, 0.f, 0.f};

    #pragma unroll
    for (int mi = 0; mi < 4; ++mi) {
        int row = mi * 16 + lr;
        #pragma unroll
        for (int ks = 0; ks < 4; ++ks) {
            int off = (row << 8) + (((ks << 6) + (lh << 4)) ^ ((row & 7) << 4));
            short8v ah = *(short8v*)((char*)Ah + off);
            short8v al = *(short8v*)((char*)Al + off);
            #pragma unroll
            for (int ni = 0; ni < 2; ++ni) {
                acc[mi][ni] = __builtin_amdgcn_mfma_f32_16x16x32_bf16(ah, bhi[ni][ks], acc[mi][ni], 0, 0, 0);
                acc[mi][ni] = __builtin_amdgcn_mfma_f32_16x16x32_bf16(ah, blo[ni][ks], acc[mi][ni], 0, 0, 0);
                acc[mi][ni] = __builtin_amdgcn_mfma_f32_16x16x32_bf16(al, bhi[ni][ks], acc[mi][ni], 0, 0, 0);
            }
        }
    }

    #pragma unroll
    for (int mi = 0; mi < 4; ++mi) {
        #pragma unroll
        for (int ni = 0; ni < 2; ++ni) {
            #pragma unroll
            for (int r = 0; r < 4; ++r) {
                int row = row0 + mi * 16 + lh * 4 + r;
                if (row < M) {
                    float v = acc[mi][ni][r];
                    unsigned short h = f2bf(v);
                    size_t o = (size_t)row * 128 + n0 + ni * 16 + lr;
                    Chi[o] = h;
                    Clo[o] = f2bf(v - bf2f(h));
                }
            }
        }
    }
}

// ---- GEMM layers 2,3: plane input, plane output (staging = pure copy) ----
__launch_bounds__(256)
__global__ void gemm128_planes_kernel(const unsigned short* __restrict__ Ahi_g,
                                      const unsigned short* __restrict__ Alo_g,
                                      const unsigned short* __restrict__ Wcvt,
                                      unsigned short* __restrict__ Chi, unsigned short* __restrict__ Clo, int M) {
    __shared__ unsigned short Ah[64 * 128];
    __shared__ unsigned short Al[64 * 128];
    int t = threadIdx.x;
    int l = t & 63, w = t >> 6;
    int lr = l & 15, lh = l >> 4;

    const unsigned short* Whi = Wcvt;
    const unsigned short* Wlo = Wcvt + 128 * 128;
    short8v bhi[2][4], blo[2][4];
    int n0 = w * 32;
    #pragma unroll
    for (int ni = 0; ni < 2; ++ni) {
        int n = n0 + ni * 16 + lr;
        #pragma unroll
        for (int ks = 0; ks < 4; ++ks) {
            bhi[ni][ks] = *(const short8v*)&Whi[n * 128 + ks * 32 + lh * 8];
            blo[ni][ks] = *(const short8v*)&Wlo[n * 128 + ks * 32 + lh * 8];
        }
    }

    int row0 = blockIdx.x * 64;
    #pragma unroll
    for (int c = 0; c < 4; ++c) {
        int chunk = c * 256 + t;
        int r  = chunk >> 4;
        int kc = chunk & 15;
        int gr = row0 + r; if (gr >= M) gr = M - 1;
        int off = (r << 8) + ((kc << 4) ^ ((r & 7) << 4));
        *(short8v*)((char*)Ah + off) = *(const short8v*)&Ahi_g[(size_t)gr * 128 + kc * 8];
        *(short8v*)((char*)Al + off) = *(const short8v*)&Alo_g[(size_t)gr * 128 + kc * 8];
    }
    __syncthreads();

    f32x4 acc[4][2];
    #pragma unroll
    for (int mi = 0; mi < 4; ++mi)
        #pragma unroll
        for (int ni = 0; ni < 2; ++ni)
            acc[mi][ni] = (f32x4){0.f, 0.f, 0.f, 0.f};

    #pragma unroll
    for (int mi = 0; mi < 4; ++mi) {
        int row = mi * 16 + lr;
        #pragma unroll
        for (int ks = 0; ks < 4; ++ks) {
            int off = (row << 8) + (((ks << 6) + (lh << 4)) ^ ((row & 7) << 4));
            short8v ah = *(short8v*)((char*)Ah + off);
            short8v al = *(short8v*)((char*)Al + off);
            #pragma unroll
            for (int ni = 0; ni < 2; ++ni) {
                acc[mi][ni] = __builtin_amdgcn_mfma_f32_16x16x32_bf16(ah, bhi[ni][ks], acc[mi][ni], 0, 0, 0);
                acc[mi][ni] = __builtin_amdgcn_mfma_f32_16x16x32_bf16(ah, blo[ni][ks], acc[mi][ni], 0, 0, 0);
                acc[mi][ni] = __builtin_amdgcn_mfma_f32_16x16x32_bf16(al, bhi[ni][ks], acc[mi][ni], 0, 0, 0);
            }
        }
    }

    #pragma unroll
    for (int mi = 0; mi < 4; ++mi) {
        #pragma unroll
        for (int ni = 0; ni < 2; ++ni) {
            #pragma unroll
            for (int r = 0; r < 4; ++r) {
                int row = row0 + mi * 16 + lh * 4 + r;
                if (row < M) {
                    float v = acc[mi][ni][r];
                    unsigned short h = f2bf(v);
                    size_t o = (size_t)row * 128 + n0 + ni * 16 + lr;
                    Chi[o] = h;
                    Clo[o] = f2bf(v - bf2f(h));
                }
            }
        }
    }
}

// ---------------- CSR aggregate + bias + relu (plane in / plane out) ----------
__launch_bounds__(256)
__global__ void aggregate_kernel(const ushort4* __restrict__ hhi, const ushort4* __restrict__ hlo,
                                 const float* __restrict__ dinv,
                                 const int* __restrict__ rowptr, const int2* __restrict__ col2,
                                 const float* __restrict__ bias,
                                 ushort4* __restrict__ ohi, ushort4* __restrict__ olo, int n) {
    int node = blockIdx.x * 8 + (threadIdx.x >> 5);
    if (node >= n) return;
    int l = threadIdx.x & 31;
    float dn = dinv[node];
    size_t rowbase = (size_t)node * 32;
    ushort4 sh = hhi[rowbase + l], sl = hlo[rowbase + l];
    float4 acc;
    acc.x = (bf2f(sh.x) + bf2f(sl.x)) * dn;
    acc.y = (bf2f(sh.y) + bf2f(sl.y)) * dn;
    acc.z = (bf2f(sh.z) + bf2f(sl.z)) * dn;
    acc.w = (bf2f(sh.w) + bf2f(sl.w)) * dn;
    int e = rowptr[node], e1 = rowptr[node + 1];
    for (; e + 8 <= e1; e += 8) {
        int2 c[8];
        #pragma unroll
        for (int j = 0; j < 8; ++j) c[j] = col2[e + j];
        ushort4 vh[8], vl[8];
        #pragma unroll
        for (int j = 0; j < 8; ++j) {
            size_t b = (size_t)c[j].x * 32 + l;
            vh[j] = hhi[b];
            vl[j] = hlo[b];
        }
        #pragma unroll
        for (int j = 0; j < 8; ++j) {
            float ds = __int_as_float(c[j].y);
            acc.x += bf2f(vh[j].x) * ds; acc.y += bf2f(vh[j].y) * ds;
            acc.z += bf2f(vh[j].z) * ds; acc.w += bf2f(vh[j].w) * ds;
            acc.x += bf2f(vl[j].x) * ds; acc.y += bf2f(vl[j].y) * ds;
            acc.z += bf2f(vl[j].z) * ds; acc.w += bf2f(vl[j].w) * ds;
        }
    }
    for (; e + 4 <= e1; e += 4) {
        int2 c[4];
        #pragma unroll
        for (int j = 0; j < 4; ++j) c[j] = col2[e + j];
        ushort4 vh[4], vl[4];
        #pragma unroll
        for (int j = 0; j < 4; ++j) {
            size_t b = (size_t)c[j].x * 32 + l;
            vh[j] = hhi[b];
            vl[j] = hlo[b];
        }
        #pragma unroll
        for (int j = 0; j < 4; ++j) {
            float ds = __int_as_float(c[j].y);
            acc.x += bf2f(vh[j].x) * ds; acc.y += bf2f(vh[j].y) * ds;
            acc.z += bf2f(vh[j].z) * ds; acc.w += bf2f(vh[j].w) * ds;
            acc.x += bf2f(vl[j].x) * ds; acc.y += bf2f(vl[j].y) * ds;
            acc.z += bf2f(vl[j].z) * ds; acc.w += bf2f(vl[j].w) * ds;
        }
    }
    for (; e < e1; ++e) {
        int2 c = col2[e];
        float ds = __int_as_float(c.y);
        size_t b = (size_t)c.x * 32 + l;
        ushort4 vh = hhi[b], vl = hlo[b];
        acc.x += (bf2f(vh.x) + bf2f(vl.x)) * ds;
        acc.y += (bf2f(vh.y) + bf2f(vl.y)) * ds;
        acc.z += (bf2f(vh.z) + bf2f(vl.z)) * ds;
        acc.w += (bf2f(vh.w) + bf2f(vl.w)) * ds;
    }
    float4 bv = *(const float4*)&bias[l * 4];
    float ox = fmaxf(acc.x * dn + bv.x, 0.f);
    float oy = fmaxf(acc.y * dn + bv.y, 0.f);
    float oz = fmaxf(acc.z * dn + bv.z, 0.f);
    float ow = fmaxf(acc.w * dn + bv.w, 0.f);
    ushort4 oh, ol;
    oh.x = f2bf(ox); ol.x = f2bf(ox - bf2f(oh.x));
    oh.y = f2bf(oy); ol.y = f2bf(oy - bf2f(oh.y));
    oh.z = f2bf(oz); ol.z = f2bf(oz - bf2f(oh.z));
    oh.w = f2bf(ow); ol.w = f2bf(ow - bf2f(oh.w));
    ohi[rowbase + l] = oh;
    olo[rowbase + l] = ol;
}

// ---------------- MFMA final layer (plane input, f32 out) ----------------
__launch_bounds__(256)
__global__ void final_planes_kernel(const unsigned short* __restrict__ Ahi_g,
                                    const unsigned short* __restrict__ Alo_g,
                                    const unsigned short* __restrict__ Wcvt,
                                    const float* __restrict__ bf, float* __restrict__ C, int M) {
    __shared__ unsigned short Ah[64 * 128];
    __shared__ unsigned short Al[64 * 128];
    int t = threadIdx.x;
    int l = t & 63, w = t >> 6;
    int lr = l & 15, lh = l >> 4;

    const unsigned short* Whi = Wcvt;            // [48n][128k]
    const unsigned short* Wlo = Wcvt + 48 * 128;
    short8v bhi[3][4], blo[3][4];
    #pragma unroll
    for (int nt = 0; nt < 3; ++nt) {
        int n = nt * 16 + lr;
        #pragma unroll
        for (int ks = 0; ks < 4; ++ks) {
            bhi[nt][ks] = *(const short8v*)&Whi[n * 128 + ks * 32 + lh * 8];
            blo[nt][ks] = *(const short8v*)&Wlo[n * 128 + ks * 32 + lh * 8];
        }
    }

    int row0 = blockIdx.x * 64;
    #pragma unroll
    for (int c = 0; c < 4; ++c) {
        int chunk = c * 256 + t;
        int r  = chunk >> 4;
        int kc = chunk & 15;
        int gr = row0 + r; if (gr >= M) gr = M - 1;
        int off = (r << 8) + ((kc << 4) ^ ((r & 7) << 4));
        *(short8v*)((char*)Ah + off) = *(const short8v*)&Ahi_g[(size_t)gr * 128 + kc * 8];
        *(short8v*)((char*)Al + off) = *(const short8v*)&Alo_g[(size_t)gr * 128 + kc * 8];
    }
    __syncthreads();

    f32x4 acc[3];
    #pragma unroll
    for (int nt = 0; nt < 3; ++nt) acc[nt] = (f32x4){0.f, 0.f, 0.f, 0.f};
    int row = w * 16 + lr;
    #pragma unroll
    for (int ks = 0; ks < 4; ++ks) {
        int off = (row << 8) + (((ks << 6) + (lh << 4)) ^ ((row & 7) << 4));
        short8v ah = *(short8v*)((char*)Ah + off);
        short8v al = *(short8v*)((char*)Al + off);
        #pragma unroll
        for (int nt = 0; nt < 3; ++nt) {
            acc[nt] = __builtin_amdgcn_mfma_f32_16x16x32_bf16(ah, bhi[nt][ks], acc[nt], 0, 0, 0);
            acc[nt] = __builtin_amdgcn_mfma_f32_16x16x32_bf16(ah, blo[nt][ks], acc[nt], 0, 0, 0);
            acc[nt] = __builtin_amdgcn_mfma_f32_16x16x32_bf16(al, bhi[nt][ks], acc[nt], 0, 0, 0);
        }
    }
    #pragma unroll
    for (int nt = 0; nt < 3; ++nt) {
        int col = nt * 16 + lr;
        #pragma unroll
        for (int r = 0; r < 4; ++r) {
            int ro = row0 + w * 16 + lh * 4 + r;
            if (col < NC && ro < M) C[(size_t)ro * NC + col] = acc[nt][r] + bf[col];
        }
    }
}

extern "C" void kernel_launch(void* const* d_in, const int* in_sizes, int n_in,
                              void* d_out, int out_size, void* d_ws, size_t ws_size,
                              hipStream_t stream) {
    const float* x  = (const float*)d_in[0];
    const int*   ei = (const int*)d_in[1];
    const float* W1 = (const float*)d_in[2];
    const float* b1 = (const float*)d_in[3];
    const float* Wh = (const float*)d_in[4];
    const float* bh = (const float*)d_in[5];
    const float* Wf = (const float*)d_in[6];
    const float* bf = (const float*)d_in[7];
    float* out = (float*)d_out;

    int n = in_sizes[0] / D;    // 50000
    int E = in_sizes[1] / 2;    // 800000

    char* ws = (char*)d_ws;
    size_t off = 0;
    auto alloc = [&](size_t bytes) {
        void* p = ws + off;
        off = (off + bytes + 255) & ~(size_t)255;
        return p;
    };
    unsigned short* P0hi = (unsigned short*)alloc((size_t)n * D * 2);
    unsigned short* P0lo = (unsigned short*)alloc((size_t)n * D * 2);
    unsigned short* P1hi = (unsigned short*)alloc((size_t)n * D * 2);
    unsigned short* P1lo = (unsigned short*)alloc((size_t)n * D * 2);
    int*   deg    = (int*)alloc((size_t)n * 4);
    int*   rowptr = (int*)alloc((size_t)(n + 1) * 4);
    int*   fill   = (int*)alloc((size_t)n * 4);
    int2*  col2   = (int2*)alloc((size_t)E * 8);
    float* dinv   = (float*)alloc((size_t)n * 4);
    int*   flag   = (int*)alloc(256);
    int*   bsum   = (int*)alloc(1024 * 4);
    int*   total  = (int*)alloc(256);
    unsigned short* Wc1  = (unsigned short*)alloc(2 * 128 * 128 * 2);
    unsigned short* Wch0 = (unsigned short*)alloc(2 * 128 * 128 * 2);
    unsigned short* Wch1 = (unsigned short*)alloc(2 * 128 * 128 * 2);
    unsigned short* Wcf  = (unsigned short*)alloc(2 * 48 * 128 * 2);

    int nb = (n + 511) / 512;   // 98 for n=50000 (<=1024 required by scan2)

    hipMemsetAsync(deg, 0, (size_t)n * 4, stream);
    detect_kernel<<<1, 256, 0, stream>>>(ei, flag);
    count_deg_kernel<<<(E + 255) / 256, 256, 0, stream>>>(ei, flag, deg, E);
    scan1_kernel<<<nb, 512, 0, stream>>>(deg, bsum, n);
    scan2_kernel<<<1, 1024, 0, stream>>>(bsum, total, nb);
    scan3_kernel<<<nb, 512, 0, stream>>>(deg, bsum, total, rowptr, fill, dinv, n);
    scatter_kernel<<<(E + 255) / 256, 256, 0, stream>>>(ei, flag, fill, dinv, col2, E);
    convertW_all_kernel<<<(49152 + 6144 + 255) / 256, 256, 0, stream>>>(W1, Wh, Wf, Wc1, Wch0, Wch1, Wcf);

    int gblocks = (n + 63) / 64;
    int agrid = (n + 7) / 8;

    gemm128_f32in_kernel<<<gblocks, 256, 0, stream>>>(x, Wc1, P0hi, P0lo, n);
    aggregate_kernel<<<agrid, 256, 0, stream>>>((const ushort4*)P0hi, (const ushort4*)P0lo, dinv, rowptr, col2, b1,
                                                (ushort4*)P1hi, (ushort4*)P1lo, n);
    gemm128_planes_kernel<<<gblocks, 256, 0, stream>>>(P1hi, P1lo, Wch0, P0hi, P0lo, n);
    aggregate_kernel<<<agrid, 256, 0, stream>>>((const ushort4*)P0hi, (const ushort4*)P0lo, dinv, rowptr, col2, bh,
                                                (ushort4*)P1hi, (ushort4*)P1lo, n);
    gemm128_planes_kernel<<<gblocks, 256, 0, stream>>>(P1hi, P1lo, Wch1, P0hi, P0lo, n);
    aggregate_kernel<<<agrid, 256, 0, stream>>>((const ushort4*)P0hi, (const ushort4*)P0lo, dinv, rowptr, col2, bh + D,
                                                (ushort4*)P1hi, (ushort4*)P1lo, n);
    final_planes_kernel<<<gblocks, 256, 0, stream>>>(P1hi, P1lo, Wcf, bf, out, n);
}

// Round 7
// 332.402 us; speedup vs baseline: 1.0656x; 1.0656x over previous
//
#include <hip/hip_runtime.h>

#define D 128
#define NC 40

typedef __attribute__((ext_vector_type(8))) short short8v;
typedef __attribute__((ext_vector_type(4))) float f32x4;

__device__ __forceinline__ unsigned short f2bf(float f) {
    unsigned u = __float_as_uint(f);
    u += 0x7fff + ((u >> 16) & 1);          // RNE
    return (unsigned short)(u >> 16);
}
__device__ __forceinline__ float bf2f(unsigned short h) {
    return __uint_as_float(((unsigned)h) << 16);
}

__device__ __forceinline__ int load_idx(const int* ei, long long pos, int is64) {
    return is64 ? ei[pos * 2] : ei[pos];
}

// per-wave int64-vs-int32 detection: check high dwords of first 64 entries
__device__ __forceinline__ int detect64(const int* __restrict__ ei) {
    int lane = threadIdx.x & 63;
    int hi = ei[lane * 2 + 1];
    return __any(hi != 0) ? 0 : 1;
}

// ---------------- graph build ----------------

// count degrees (edge blocks) + convert all weights to hi/lo bf16 planes (extra blocks)
__global__ void count_convert_kernel(const int* __restrict__ ei, int* __restrict__ deg,
                                     int E, int EB,
                                     const float* __restrict__ W1, const float* __restrict__ Wh,
                                     const float* __restrict__ Wf,
                                     unsigned short* __restrict__ Wc1, unsigned short* __restrict__ Wch0,
                                     unsigned short* __restrict__ Wch1, unsigned short* __restrict__ Wcf) {
    if (blockIdx.x < EB) {
        int is64 = detect64(ei);
        int e = blockIdx.x * 256 + threadIdx.x;
        if (e < E) {
            int d = load_idx(ei, (long long)E + e, is64);   // dst
            atomicAdd(&deg[d], 1);
        }
    } else {
        int idx = (blockIdx.x - EB) * 256 + threadIdx.x;    // 0 .. 55295
        if (idx < 49152) {
            int which = idx >> 14;                           // 0,1,2
            int j = idx & 16383;
            int nn = j >> 7, k = j & 127;
            const float* W = (which == 0) ? W1 : (which == 1) ? Wh : Wh + 16384;
            unsigned short* o = (which == 0) ? Wc1 : (which == 1) ? Wch0 : Wch1;
            float v = W[k * 128 + nn];
            unsigned short h = f2bf(v);
            o[j] = h;
            o[16384 + j] = f2bf(v - bf2f(h));
        } else if (idx < 49152 + 6144) {
            int j = idx - 49152;
            int nn = j >> 7, k = j & 127;
            float v = (nn < NC) ? Wf[k * NC + nn] : 0.f;
            unsigned short h = f2bf(v);
            Wcf[j] = h;
            Wcf[6144 + j] = f2bf(v - bf2f(h));
        }
    }
}

// phase 1: per-block (512) sums of deg
__global__ void scan1_kernel(const int* __restrict__ deg, int* __restrict__ bsum, int m) {
    int i = blockIdx.x * 512 + threadIdx.x;
    int v = (i < m) ? deg[i] : 0;
    #pragma unroll
    for (int off = 32; off; off >>= 1) v += __shfl_down(v, off, 64);
    __shared__ int ws[8];
    if ((threadIdx.x & 63) == 0) ws[threadIdx.x >> 6] = v;
    __syncthreads();
    if (threadIdx.x == 0) {
        int s = 0;
        #pragma unroll
        for (int j = 0; j < 8; ++j) s += ws[j];
        bsum[blockIdx.x] = s;
    }
}

// phase 2 (fused scan2+scan3): inline prefix over bsum (nb<=512) + local scan
// + rowptr/fill/dinv emit. rowptr[n] = E statically.
__global__ void scan3_kernel(const int* __restrict__ deg, const int* __restrict__ bsum,
                             int* __restrict__ rowptr, int* __restrict__ fill,
                             float* __restrict__ dinv, int n, int E, int nb) {
    int t = threadIdx.x;                       // 512
    int lane = t & 63, w = t >> 6;
    // inline: base = sum_{j < blockIdx} bsum[j]
    int pv = (t < nb && t < (int)blockIdx.x) ? bsum[t] : 0;
    int rs = pv;
    #pragma unroll
    for (int off = 32; off; off >>= 1) rs += __shfl_down(rs, off, 64);
    __shared__ int red[8];
    if (lane == 0) red[w] = rs;
    __syncthreads();
    int base = 0;
    #pragma unroll
    for (int j = 0; j < 8; ++j) base += red[j];
    __syncthreads();

    int i = blockIdx.x * 512 + t;
    int v = (i < n) ? deg[i] : 0;
    int s = v;
    #pragma unroll
    for (int off = 1; off < 64; off <<= 1) {
        int x = __shfl_up(s, off, 64);
        if (lane >= off) s += x;
    }
    __shared__ int wsum[8];
    if (lane == 63) wsum[w] = s;
    __syncthreads();
    int wbase = 0;
    #pragma unroll
    for (int j = 0; j < 8; ++j) if (j < w) wbase += wsum[j];
    int excl = base + wbase + s - v;
    if (i < n) {
        rowptr[i] = excl;
        fill[i]   = excl;
        dinv[i]   = rsqrtf((float)(v + 1));   // +1 self loop
    }
    if (i == 0) rowptr[n] = E;
}

// scatter edge -> CSR, packing {src, dinv[src]}
__global__ void scatter_kernel(const int* __restrict__ ei, int* __restrict__ fill,
                               const float* __restrict__ dinv, int2* __restrict__ col2, int E) {
    int is64 = detect64(ei);
    int e = blockIdx.x * 256 + threadIdx.x;
    if (e >= E) return;
    int s = load_idx(ei, (long long)e, is64);
    int d = load_idx(ei, (long long)E + e, is64);
    int pos = atomicAdd(&fill[d], 1);
    col2[pos] = make_int2(s, __float_as_int(dinv[s]));
}

// ---------------- fused layer: out = relu( agg(h) @ W + b ) ----------------
// agg(h@W) == agg(h)@W (both linear). Block owns 16 nodes; 16 lanes/node gather
// (2 float4 per lane = full 512B row across 16 lanes; 128 chains/CU);
// aggregated rows -> LDS split-bf16 planes (XOR swizzle) -> 16x16x32 MFMA
// epilogue (C = Ah*Wh + Ah*Wl + Al*Wh) -> bias+relu -> f32 rows out.
__launch_bounds__(256)
__global__ void fused_layer_kernel(const float4* __restrict__ h4,
                                   const unsigned short* __restrict__ Wcvt,  // [128n][128k] hi,lo
                                   const float* __restrict__ bias,
                                   const float* __restrict__ dinv,
                                   const int* __restrict__ rowptr, const int2* __restrict__ col2,
                                   float* __restrict__ out, int n) {
    __shared__ unsigned short Ah[16 * 128];    // 4KB
    __shared__ unsigned short Al[16 * 128];    // 4KB
    int t = threadIdx.x;
    int g = t >> 4, l16 = t & 15;              // node group, lane-in-group
    int node = blockIdx.x * 16 + g;
    int nd = (node < n) ? node : (n - 1);
    float dn = dinv[nd];
    size_t rowbase = (size_t)nd * 32;

    // self loop
    float4 a0 = h4[rowbase + l16];
    float4 a1 = h4[rowbase + l16 + 16];
    float4 acc0, acc1;
    acc0.x = a0.x * dn; acc0.y = a0.y * dn; acc0.z = a0.z * dn; acc0.w = a0.w * dn;
    acc1.x = a1.x * dn; acc1.y = a1.y * dn; acc1.z = a1.z * dn; acc1.w = a1.w * dn;

    int e = rowptr[nd], e1 = rowptr[nd + 1];
    for (; e + 4 <= e1; e += 4) {
        int2 c[4];
        #pragma unroll
        for (int j = 0; j < 4; ++j) c[j] = col2[e + j];
        float4 v0[4], v1[4];
        #pragma unroll
        for (int j = 0; j < 4; ++j) {
            size_t b = (size_t)c[j].x * 32;
            v0[j] = h4[b + l16];
            v1[j] = h4[b + l16 + 16];
        }
        #pragma unroll
        for (int j = 0; j < 4; ++j) {
            float ds = __int_as_float(c[j].y);
            acc0.x += v0[j].x * ds; acc0.y += v0[j].y * ds;
            acc0.z += v0[j].z * ds; acc0.w += v0[j].w * ds;
            acc1.x += v1[j].x * ds; acc1.y += v1[j].y * ds;
            acc1.z += v1[j].z * ds; acc1.w += v1[j].w * ds;
        }
    }
    for (; e < e1; ++e) {
        int2 c = col2[e];
        float ds = __int_as_float(c.y);
        size_t b = (size_t)c.x * 32;
        float4 v0 = h4[b + l16], v1 = h4[b + l16 + 16];
        acc0.x += v0.x * ds; acc0.y += v0.y * ds; acc0.z += v0.z * ds; acc0.w += v0.w * ds;
        acc1.x += v1.x * ds; acc1.y += v1.y * ds; acc1.z += v1.z * ds; acc1.w += v1.w * ds;
    }
    // aggregated value = acc * dn (bias comes after transform)
    acc0.x *= dn; acc0.y *= dn; acc0.z *= dn; acc0.w *= dn;
    acc1.x *= dn; acc1.y *= dn; acc1.z *= dn; acc1.w *= dn;

    // stage to LDS planes, swizzled; lane covers k-chunks l16 and l16+16
    {
        int kc0 = l16 >> 1, sub = (l16 & 1) * 8;
        int off0 = (g << 8) + (((kc0) << 4) ^ ((g & 7) << 4)) + sub;
        int off1 = (g << 8) + (((kc0 + 8) << 4) ^ ((g & 7) << 4)) + sub;
        ushort4 h0, l0, h1, l1;
        h0.x = f2bf(acc0.x); l0.x = f2bf(acc0.x - bf2f(h0.x));
        h0.y = f2bf(acc0.y); l0.y = f2bf(acc0.y - bf2f(h0.y));
        h0.z = f2bf(acc0.z); l0.z = f2bf(acc0.z - bf2f(h0.z));
        h0.w = f2bf(acc0.w); l0.w = f2bf(acc0.w - bf2f(h0.w));
        h1.x = f2bf(acc1.x); l1.x = f2bf(acc1.x - bf2f(h1.x));
        h1.y = f2bf(acc1.y); l1.y = f2bf(acc1.y - bf2f(h1.y));
        h1.z = f2bf(acc1.z); l1.z = f2bf(acc1.z - bf2f(h1.z));
        h1.w = f2bf(acc1.w); l1.w = f2bf(acc1.w - bf2f(h1.w));
        *(ushort4*)((char*)Ah + off0) = h0;
        *(ushort4*)((char*)Al + off0) = l0;
        *(ushort4*)((char*)Ah + off1) = h1;
        *(ushort4*)((char*)Al + off1) = l1;
    }
    __syncthreads();

    // MFMA: 4 waves x 32 cols each, M=16 rows (the block's 16 nodes)
    int l = t & 63, wv = t >> 6;
    int lr = l & 15, lh = l >> 4;
    const unsigned short* Whi = Wcvt;
    const unsigned short* Wlo = Wcvt + 128 * 128;
    f32x4 o0 = (f32x4){0.f, 0.f, 0.f, 0.f};
    f32x4 o1 = (f32x4){0.f, 0.f, 0.f, 0.f};
    int n0 = wv * 32;
    #pragma unroll
    for (int ks = 0; ks < 4; ++ks) {
        int aoff = (lr << 8) + (((ks << 6) + (lh << 4)) ^ ((lr & 7) << 4));
        short8v ah = *(short8v*)((char*)Ah + aoff);
        short8v al = *(short8v*)((char*)Al + aoff);
        int c0 = (n0 + lr) * 128 + ks * 32 + lh * 8;
        int c1 = (n0 + 16 + lr) * 128 + ks * 32 + lh * 8;
        short8v bh0 = *(const short8v*)&Whi[c0];
        short8v bl0 = *(const short8v*)&Wlo[c0];
        short8v bh1 = *(const short8v*)&Whi[c1];
        short8v bl1 = *(const short8v*)&Wlo[c1];
        o0 = __builtin_amdgcn_mfma_f32_16x16x32_bf16(ah, bh0, o0, 0, 0, 0);
        o0 = __builtin_amdgcn_mfma_f32_16x16x32_bf16(ah, bl0, o0, 0, 0, 0);
        o0 = __builtin_amdgcn_mfma_f32_16x16x32_bf16(al, bh0, o0, 0, 0, 0);
        o1 = __builtin_amdgcn_mfma_f32_16x16x32_bf16(ah, bh1, o1, 0, 0, 0);
        o1 = __builtin_amdgcn_mfma_f32_16x16x32_bf16(ah, bl1, o1, 0, 0, 0);
        o1 = __builtin_amdgcn_mfma_f32_16x16x32_bf16(al, bh1, o1, 0, 0, 0);
    }
    // epilogue: bias + relu, D layout col=lane&15, row=(lane>>4)*4+r
    float b0 = bias[n0 + lr], b1v = bias[n0 + 16 + lr];
    #pragma unroll
    for (int r = 0; r < 4; ++r) {
        int row = blockIdx.x * 16 + lh * 4 + r;
        if (row < n) {
            out[(size_t)row * 128 + n0 + lr]      = fmaxf(o0[r] + b0, 0.f);
            out[(size_t)row * 128 + n0 + 16 + lr] = fmaxf(o1[r] + b1v, 0.f);
        }
    }
}

// ---------------- MFMA final layer  C[M x 40] = A[M x 128] @ Wf + bf (r5 proven) ----
__launch_bounds__(256)
__global__ void final_mfma_kernel(const float* __restrict__ A, const unsigned short* __restrict__ Wcvt,
                                  const float* __restrict__ bf, float* __restrict__ C, int M) {
    __shared__ unsigned short Ah[64 * 128];
    __shared__ unsigned short Al[64 * 128];
    int t = threadIdx.x;
    int l = t & 63, w = t >> 6;
    int lr = l & 15, lh = l >> 4;

    const unsigned short* Whi = Wcvt;            // [48n][128k]
    const unsigned short* Wlo = Wcvt + 48 * 128;
    short8v bhi[3][4], blo[3][4];
    #pragma unroll
    for (int nt = 0; nt < 3; ++nt) {
        int n = nt * 16 + lr;
        #pragma unroll
        for (int ks = 0; ks < 4; ++ks) {
            bhi[nt][ks] = *(const short8v*)&Whi[n * 128 + ks * 32 + lh * 8];
            blo[nt][ks] = *(const short8v*)&Wlo[n * 128 + ks * 32 + lh * 8];
        }
    }

    int row0 = blockIdx.x * 64;
    #pragma unroll
    for (int c = 0; c < 4; ++c) {
        int chunk = c * 256 + t;
        int r  = chunk >> 4;
        int kc = chunk & 15;
        int gr = row0 + r; if (gr >= M) gr = M - 1;
        float4 a0 = *(const float4*)&A[(size_t)gr * 128 + kc * 8];
        float4 a1 = *(const float4*)&A[(size_t)gr * 128 + kc * 8 + 4];
        float av[8] = {a0.x, a0.y, a0.z, a0.w, a1.x, a1.y, a1.z, a1.w};
        short8v hv, lv;
        #pragma unroll
        for (int j = 0; j < 8; ++j) {
            unsigned short hi = f2bf(av[j]);
            hv[j] = (short)hi;
            lv[j] = (short)f2bf(av[j] - bf2f(hi));
        }
        int off = (r << 8) + ((kc << 4) ^ ((r & 7) << 4));
        *(short8v*)((char*)Ah + off) = hv;
        *(short8v*)((char*)Al + off) = lv;
    }
    __syncthreads();

    f32x4 acc[3];
    #pragma unroll
    for (int nt = 0; nt < 3; ++nt) acc[nt] = (f32x4){0.f, 0.f, 0.f, 0.f};
    int row = w * 16 + lr;
    #pragma unroll
    for (int ks = 0; ks < 4; ++ks) {
        int off = (row << 8) + (((ks << 6) + (lh << 4)) ^ ((row & 7) << 4));
        short8v ah = *(short8v*)((char*)Ah + off);
        short8v al = *(short8v*)((char*)Al + off);
        #pragma unroll
        for (int nt = 0; nt < 3; ++nt) {
            acc[nt] = __builtin_amdgcn_mfma_f32_16x16x32_bf16(ah, bhi[nt][ks], acc[nt], 0, 0, 0);
            acc[nt] = __builtin_amdgcn_mfma_f32_16x16x32_bf16(ah, blo[nt][ks], acc[nt], 0, 0, 0);
            acc[nt] = __builtin_amdgcn_mfma_f32_16x16x32_bf16(al, bhi[nt][ks], acc[nt], 0, 0, 0);
        }
    }
    #pragma unroll
    for (int nt = 0; nt < 3; ++nt) {
        int col = nt * 16 + lr;
        #pragma unroll
        for (int r = 0; r < 4; ++r) {
            int ro = row0 + w * 16 + lh * 4 + r;
            if (col < NC && ro < M) C[(size_t)ro * NC + col] = acc[nt][r] + bf[col];
        }
    }
}

extern "C" void kernel_launch(void* const* d_in, const int* in_sizes, int n_in,
                              void* d_out, int out_size, void* d_ws, size_t ws_size,
                              hipStream_t stream) {
    const float* x  = (const float*)d_in[0];
    const int*   ei = (const int*)d_in[1];
    const float* W1 = (const float*)d_in[2];
    const float* b1 = (const float*)d_in[3];
    const float* Wh = (const float*)d_in[4];
    const float* bh = (const float*)d_in[5];
    const float* Wf = (const float*)d_in[6];
    const float* bf = (const float*)d_in[7];
    float* out = (float*)d_out;

    int n = in_sizes[0] / D;    // 50000
    int E = in_sizes[1] / 2;    // 800000

    char* ws = (char*)d_ws;
    size_t off = 0;
    auto alloc = [&](size_t bytes) {
        void* p = ws + off;
        off = (off + bytes + 255) & ~(size_t)255;
        return p;
    };
    float* B0     = (float*)alloc((size_t)n * D * 4);
    float* B1     = (float*)alloc((size_t)n * D * 4);
    int*   deg    = (int*)alloc((size_t)n * 4);
    int*   rowptr = (int*)alloc((size_t)(n + 1) * 4);
    int*   fill   = (int*)alloc((size_t)n * 4);
    int2*  col2   = (int2*)alloc((size_t)E * 8);
    float* dinv   = (float*)alloc((size_t)n * 4);
    int*   bsum   = (int*)alloc(1024 * 4);
    unsigned short* Wc1  = (unsigned short*)alloc(2 * 128 * 128 * 2);
    unsigned short* Wch0 = (unsigned short*)alloc(2 * 128 * 128 * 2);
    unsigned short* Wch1 = (unsigned short*)alloc(2 * 128 * 128 * 2);
    unsigned short* Wcf  = (unsigned short*)alloc(2 * 48 * 128 * 2);

    int EB = (E + 255) / 256;          // edge blocks
    int CB = (49152 + 6144 + 255) / 256;  // convert blocks
    int nb = (n + 511) / 512;          // 98

    hipMemsetAsync(deg, 0, (size_t)n * 4, stream);
    count_convert_kernel<<<EB + CB, 256, 0, stream>>>(ei, deg, E, EB, W1, Wh, Wf, Wc1, Wch0, Wch1, Wcf);
    scan1_kernel<<<nb, 512, 0, stream>>>(deg, bsum, n);
    scan3_kernel<<<nb, 512, 0, stream>>>(deg, bsum, rowptr, fill, dinv, n, E, nb);
    scatter_kernel<<<EB, 256, 0, stream>>>(ei, fill, dinv, col2, E);

    int fgrid = (n + 15) / 16;

    fused_layer_kernel<<<fgrid, 256, 0, stream>>>((const float4*)x, Wc1, b1, dinv, rowptr, col2, B0, n);
    fused_layer_kernel<<<fgrid, 256, 0, stream>>>((const float4*)B0, Wch0, bh, dinv, rowptr, col2, B1, n);
    fused_layer_kernel<<<fgrid, 256, 0, stream>>>((const float4*)B1, Wch1, bh + D, dinv, rowptr, col2, B0, n);
    final_mfma_kernel<<<(n + 63) / 64, 256, 0, stream>>>(B0, Wcf, bf, out, n);
}